// Round 2
// baseline (507.087 us; speedup 1.0000x reference)
//
#include <hip/hip_runtime.h>

#define D 32
#define K_CODES 8192
#define ROWS_PB 32
#define TPB 256

// Map float -> unsigned such that unsigned order == float order (all floats).
__device__ __forceinline__ unsigned sortkey(float f) {
    unsigned b = __float_as_uint(f);
    return b ^ ((unsigned)((int)b >> 31) | 0x80000000u);
}

__global__ __launch_bounds__(TPB) void vq_main(
    const float* __restrict__ x, const float* __restrict__ cb,
    float* __restrict__ out, unsigned* __restrict__ minD,
    unsigned* __restrict__ used, float* __restrict__ mse_accum)
{
    __shared__ float xs[ROWS_PB][D];
    __shared__ float xx[ROWS_PB];
    __shared__ unsigned tokS[ROWS_PB];
    __shared__ unsigned long long wbest[4][ROWS_PB];
    __shared__ float pp[4];

    const int tid = threadIdx.x;
    const long row0 = (long)blockIdx.x * ROWS_PB;

    // Stage 32 rows (4 KB) into LDS, coalesced float4.
    ((float4*)xs)[tid] = ((const float4*)(x + row0 * D))[tid];
    __syncthreads();
    if (tid < ROWS_PB) {
        float s = 0.f;
        #pragma unroll
        for (int d = 0; d < D; ++d) s += xs[tid][d] * xs[tid][d];
        xx[tid] = s;
    }
    __syncthreads();

    // Per-row best over this thread's codes: packed (sortkey(score)<<32)|~k.
    unsigned long long best[ROWS_PB];
    #pragma unroll
    for (int r = 0; r < ROWS_PB; ++r) best[r] = 0ull;

    for (int j = 0; j < K_CODES / (2 * TPB); ++j) {
        const int k0 = tid + j * TPB;
        const int k1 = k0 + K_CODES / 2;
        const float4* p0 = (const float4*)(cb + (long)k0 * D);
        const float4* p1 = (const float4*)(cb + (long)k1 * D);
        float4 c0[8], c1[8];
        #pragma unroll
        for (int q = 0; q < 8; ++q) { c0[q] = p0[q]; c1[q] = p1[q]; }
        float C0 = 0.f, C1 = 0.f;
        #pragma unroll
        for (int q = 0; q < 8; ++q) {
            C0 += c0[q].x*c0[q].x + c0[q].y*c0[q].y + c0[q].z*c0[q].z + c0[q].w*c0[q].w;
            C1 += c1[q].x*c1[q].x + c1[q].y*c1[q].y + c1[q].z*c1[q].z + c1[q].w*c1[q].w;
        }
        float md0 = 3.0e38f, md1 = 3.0e38f;
        #pragma unroll
        for (int r = 0; r < ROWS_PB; ++r) {
            const float4* xr = (const float4*)xs[r];
            float d0 = 0.f, d1 = 0.f;
            #pragma unroll
            for (int q = 0; q < 8; ++q) {
                float4 xv = xr[q];   // LDS broadcast (all lanes same addr)
                d0 += c0[q].x*xv.x; d0 += c0[q].y*xv.y;
                d0 += c0[q].z*xv.z; d0 += c0[q].w*xv.w;
                d1 += c1[q].x*xv.x; d1 += c1[q].y*xv.y;
                d1 += c1[q].z*xv.z; d1 += c1[q].w*xv.w;
            }
            // score s = 2*x.c - ||c||^2 ; argmin dist == argmax s (||x||^2 common)
            float s0 = 2.f * d0 - C0;
            float s1 = 2.f * d1 - C1;
            unsigned long long pk0 = ((unsigned long long)sortkey(s0) << 32) | (unsigned)(~k0);
            unsigned long long pk1 = ((unsigned long long)sortkey(s1) << 32) | (unsigned)(~k1);
            unsigned long long pm = pk0 > pk1 ? pk0 : pk1;
            if (pm > best[r]) best[r] = pm;
            // full distance for entropy-loss per-code min (always > 0 here)
            md0 = fminf(md0, xx[r] - s0);
            md1 = fminf(md1, xx[r] - s1);
        }
        atomicMin(&minD[k0], __float_as_uint(md0));
        atomicMin(&minD[k1], __float_as_uint(md1));
    }

    // Reduce per-row best across the block: wave shuffle, then LDS across waves.
    const int lane = tid & 63;
    const int wid = tid >> 6;
    #pragma unroll
    for (int r = 0; r < ROWS_PB; ++r) {
        unsigned long long b = best[r];
        #pragma unroll
        for (int off = 32; off > 0; off >>= 1) {
            unsigned long long o = __shfl_xor(b, off, 64);
            if (o > b) b = o;
        }
        best[r] = b;
    }
    if (lane == 0) {
        #pragma unroll
        for (int r = 0; r < ROWS_PB; ++r) wbest[wid][r] = best[r];
    }
    __syncthreads();
    if (tid < ROWS_PB) {
        unsigned long long b = wbest[0][tid];
        if (wbest[1][tid] > b) b = wbest[1][tid];
        if (wbest[2][tid] > b) b = wbest[2][tid];
        if (wbest[3][tid] > b) b = wbest[3][tid];
        unsigned tok = ~(unsigned)(b & 0xFFFFFFFFull);
        tokS[tid] = tok;
        used[tok] = 1u;   // benign race: all writers store 1
    }
    __syncthreads();

    // Emit emb (== straight-through output values) + fused MSE partial.
    float part = 0.f;
    #pragma unroll
    for (int i = tid; i < ROWS_PB * D; i += TPB) {
        int r = i >> 5, d = i & 31;
        float e = cb[(long)tokS[r] * D + d];
        out[(row0 + r) * D + d] = e;
        float dx = e - xs[r][d];
        part += dx * dx;
    }
    #pragma unroll
    for (int off = 32; off > 0; off >>= 1) part += __shfl_xor(part, off, 64);
    if (lane == 0) pp[wid] = part;
    __syncthreads();
    if (tid == 0) atomicAdd(mse_accum, pp[0] + pp[1] + pp[2] + pp[3]);
}

__global__ __launch_bounds__(TPB) void vq_finish(
    const unsigned* __restrict__ minD, const unsigned* __restrict__ used,
    const float* __restrict__ mse_accum, float* __restrict__ out, int n_elems)
{
    __shared__ float pp[4];
    const int tid = threadIdx.x;
    float s = 0.f;
    for (int k = tid; k < K_CODES; k += TPB)
        if (used[k] == 0u) s += __uint_as_float(minD[k]);
    const int lane = tid & 63;
    const int wid = tid >> 6;
    #pragma unroll
    for (int off = 32; off > 0; off >>= 1) s += __shfl_xor(s, off, 64);
    if (lane == 0) pp[wid] = s;
    __syncthreads();
    if (tid == 0) {
        float ent = (pp[0] + pp[1] + pp[2] + pp[3]) / (float)K_CODES;
        float mse = mse_accum[0] / (float)n_elems;
        // embedding(1.0) + commitment(0.25) share the same value; entropy w=0.1
        out[n_elems] = 1.25f * mse + 0.1f * ent;
    }
}

extern "C" void kernel_launch(void* const* d_in, const int* in_sizes, int n_in,
                              void* d_out, int out_size, void* d_ws, size_t ws_size,
                              hipStream_t stream)
{
    (void)n_in; (void)out_size; (void)ws_size;
    const float* x  = (const float*)d_in[0];
    const float* cb = (const float*)d_in[1];
    float* out = (float*)d_out;
    const int n_elems = in_sizes[0];           // 524288
    const int nrows   = n_elems / D;           // 16384

    unsigned* minD      = (unsigned*)d_ws;
    unsigned* used      = (unsigned*)((char*)d_ws + K_CODES * 4);
    float*    mse_accum = (float*)   ((char*)d_ws + K_CODES * 8);

    hipMemsetAsync(minD, 0x7F, K_CODES * 4, stream);  // 0x7F7F7F7F = 3.39e38 (+inf proxy)
    hipMemsetAsync(used, 0, K_CODES * 4, stream);
    hipMemsetAsync(mse_accum, 0, 4, stream);

    vq_main<<<nrows / ROWS_PB, TPB, 0, stream>>>(x, cb, out, minD, used, mse_accum);
    vq_finish<<<1, TPB, 0, stream>>>(minD, used, mse_accum, out, n_elems);
}